// Round 1
// baseline (61.018 us; speedup 1.0000x reference)
//
#include <hip/hip_runtime.h>

// QLayer: analytic collapse of the 14-qubit circuit.
//
// Math: state before CNOT chain is a product state; per-wire
//   z_j = cos(x_proj[b,j]) * cos(sum_k params[j,k]).
// Heisenberg picture: CNOT chain maps Z_i -> Z_0 Z_1 ... Z_i, so
//   out[b,i] = prod_{j<=i} z_j.
// Whole op = (256x128)@(128x14) GEMV + bias + cos + prefix product.

#define N_QUBITS 14
#define N_PARAMS 4
#define INPUT_DIM 128

__global__ __launch_bounds__(256) void qlayer_kernel(
    const float* __restrict__ x,       // (256, 128)
    const float* __restrict__ w,       // (14, 128)  proj_w
    const float* __restrict__ bias,    // (14,)      proj_b
    const float* __restrict__ params,  // (14, 4)
    float* __restrict__ out)           // (256, 14)
{
    const int lane = threadIdx.x & 63;
    const int wave = threadIdx.x >> 6;       // 4 waves/block, 1 sample/wave
    const int b    = blockIdx.x * 4 + wave;  // batch index

    // Each lane owns 2 of the 128 input features.
    const float x0 = x[b * INPUT_DIM + lane];
    const float x1 = x[b * INPUT_DIM + 64 + lane];

    float dot[N_QUBITS];
#pragma unroll
    for (int j = 0; j < N_QUBITS; ++j) {
        float p = x0 * w[j * INPUT_DIM + lane] +
                  x1 * w[j * INPUT_DIM + 64 + lane];
        // full butterfly so every lane ends with the complete dot product
#pragma unroll
        for (int off = 32; off > 0; off >>= 1)
            p += __shfl_xor(p, off, 64);
        dot[j] = p;
    }

    // Lane i accumulates prod_{j<=i} z_j; lanes >= 14 just idle through.
    float prod = 1.0f;
#pragma unroll
    for (int j = 0; j < N_QUBITS; ++j) {
        const float P = params[j * N_PARAMS + 0] + params[j * N_PARAMS + 1] +
                        params[j * N_PARAMS + 2] + params[j * N_PARAMS + 3];
        const float z = __cosf(dot[j] + bias[j]) * __cosf(P);
        if (j <= lane) prod *= z;
    }
    if (lane < N_QUBITS)
        out[b * N_QUBITS + lane] = prod;   // 14 contiguous 4B stores
}

extern "C" void kernel_launch(void* const* d_in, const int* in_sizes, int n_in,
                              void* d_out, int out_size, void* d_ws, size_t ws_size,
                              hipStream_t stream) {
    const float* x      = (const float*)d_in[0];  // (256,128)
    const float* proj_w = (const float*)d_in[1];  // (14,128)
    const float* proj_b = (const float*)d_in[2];  // (14,)
    const float* params = (const float*)d_in[3];  // (14,4)
    float* out          = (float*)d_out;          // (256,14)

    // 256 samples, 1 wave each, 4 waves per 256-thread block -> 64 blocks
    qlayer_kernel<<<64, 256, 0, stream>>>(x, proj_w, proj_b, params, out);
}

// Round 2
// 59.693 us; speedup vs baseline: 1.0222x; 1.0222x over previous
//
#include <hip/hip_runtime.h>

// QLayer: analytic collapse of the 14-qubit circuit.
//
// Math: the pre-CNOT state is a product state; per-wire
//   z_j = cos(x_proj[b,j]) * cos(sum_k params[j,k]).
// Heisenberg picture: the CNOT chain maps Z_i -> Z_0 Z_1 ... Z_i, so
//   out[b,i] = prod_{j<=i} z_j.
// Whole op = (256x128)@(128x14) GEMV + bias + cos + prefix product.
//
// Mapping: 1 wave (64 lanes) per batch sample, 4 waves/block, 64 blocks.
// Lane l holds features {2l, 2l+1} via one float2 load; 6-stage butterfly
// per dot; z_j materialized only in lane j; 4-step shfl_up product scan.

#define N_QUBITS 14
#define N_PARAMS 4
#define INPUT_DIM 128

__global__ __launch_bounds__(256) void qlayer_kernel(
    const float* __restrict__ x,       // (256, 128)
    const float* __restrict__ w,       // (14, 128)  proj_w
    const float* __restrict__ bias,    // (14,)      proj_b
    const float* __restrict__ params,  // (14, 4)
    float* __restrict__ out)           // (256, 14)
{
    const int lane = threadIdx.x & 63;
    const int wave = threadIdx.x >> 6;
    const int b    = (blockIdx.x << 2) | wave;

    // features 2*lane, 2*lane+1 — one dwordx2 load each for x and w rows
    const float2 xv = ((const float2*)(x + b * INPUT_DIM))[lane];

    float myDot = 0.0f;  // lane j (<14) ends up holding dot_j
#pragma unroll
    for (int j = 0; j < N_QUBITS; ++j) {
        const float2 wv = ((const float2*)(w + j * INPUT_DIM))[lane];
        float p = fmaf(xv.x, wv.x, xv.y * wv.y);
#pragma unroll
        for (int off = 32; off > 0; off >>= 1)
            p += __shfl_xor(p, off, 64);
        myDot = (lane == j) ? p : myDot;   // v_cndmask, no reg array
    }

    // lane j < 14: z_j = cos(dot_j + bias_j) * cos(sum_k params[j,k])
    float z = 1.0f;
    if (lane < N_QUBITS) {
        const float P = params[lane * N_PARAMS + 0] + params[lane * N_PARAMS + 1] +
                        params[lane * N_PARAMS + 2] + params[lane * N_PARAMS + 3];
        z = __cosf(myDot + bias[lane]) * __cosf(P);
    }

    // inclusive product scan over lanes 0..13 (Hillis-Steele, 4 steps)
#pragma unroll
    for (int off = 1; off < 16; off <<= 1) {
        const float t = __shfl_up(z, off, 64);
        if (lane >= off) z *= t;
    }

    if (lane < N_QUBITS)
        out[b * N_QUBITS + lane] = z;   // 14 contiguous 4B stores per sample
}

extern "C" void kernel_launch(void* const* d_in, const int* in_sizes, int n_in,
                              void* d_out, int out_size, void* d_ws, size_t ws_size,
                              hipStream_t stream) {
    const float* x      = (const float*)d_in[0];  // (256,128)
    const float* proj_w = (const float*)d_in[1];  // (14,128)
    const float* proj_b = (const float*)d_in[2];  // (14,)
    const float* params = (const float*)d_in[3];  // (14,4)
    float* out          = (float*)d_out;          // (256,14)

    qlayer_kernel<<<64, 256, 0, stream>>>(x, proj_w, proj_b, params, out);
}